// Round 7
// baseline (602.714 us; speedup 1.0000x reference)
//
#include <hip/hip_runtime.h>

// LinearMPC PGD, round 11: ALL-REGISTER H (4 tiles/wave in unified VGPR+AGPR file).
// 128 blocks x 512 thr, __launch_bounds__(512,1): 2 waves/SIMD x 512 unified regs
// = full register file. (128 blocks <= 256 CUs -> 1 block/CU regardless; the old
// "256-reg cap" lesson conflated arch-VGPR cap with the unified budget — gfx950
// MFMA reads A/B straight from AGPRs, ~512 regs/wave spill-free per m08/m24.)
// Wave w owns cols [w*64,+64) = 4 MFMA n-tiles, ALL 64 B-fragments in registers
// (256 regs). Per-iter LDS traffic: ONLY the 16 a-reads/wave of u_bf (structural
// cross-wave u broadcast) + u-writes. No Hb workspace, no converter kernel,
// no global streams. Same RNE bf16 bytes, same MFMA order -> bit-identical output.
// Lessons: R2 column split forced (no cross-block comm); R6/R10 second global
// stream = register overflow -> in-loop sink (FETCH/WRITE rise, 2x slowdown);
// R7/R8 dbuf/single-barrier family dead; R9 loop-invariant streams are LICM'd.
// Tripwire: WRITE_SIZE blowup = spill -> revert to 3-reg-tiles + T2-LDS hybrid.

typedef unsigned short u16t;
typedef __attribute__((ext_vector_type(8))) short short8;
typedef __attribute__((ext_vector_type(4))) float floatx4;

__device__ __forceinline__ u16t f32_to_bf16(float x) {
    unsigned int u = __builtin_bit_cast(unsigned int, x);
    u = (u + 0x7FFFu + ((u >> 16) & 1u)) >> 16;   // RNE
    return (u16t)u;
}

#define MFMA(a, b, c) __builtin_amdgcn_mfma_f32_16x16x32_bf16((a), (b), (c), 0, 0, 0)

__global__ __launch_bounds__(512, 1)
void pgd_kernel11(const float* __restrict__ xref,   // [2048][65][8]
                  const float* __restrict__ H,      // [512][512] fp32
                  const float* __restrict__ Phi,    // [65][8][8]
                  const float* __restrict__ Q,      // [8][8]
                  float* __restrict__ out)          // [2048][512]
{
    __shared__ __align__(16) u16t u_bf[16][520];    // 16,640 B — the only LDS

    const int tid  = threadIdx.x;
    const int lane = tid & 63;
    const int w    = tid >> 6;        // wave 0..7
    const int quad = lane >> 4;       // 0..3
    const int lcol = lane & 15;       // 0..15
    const int b0   = blockIdx.x * 16;
    const int colbase = w * 64;

    // ---- zero u_bf ----
    {
        u16t* ub = &u_bf[0][0];
        for (int e = tid; e < 8320; e += 512) ub[e] = 0;
    }

    // ---- f (linear term) + u master, per-thread regs, C/D layout ----
    float f_reg[4][4], u_reg[4][4];
    #pragma unroll
    for (int T = 0; T < 4; ++T) {
        int c = colbase + T * 16 + lcol;
        int k = c >> 3, i = c & 7;
        #pragma unroll
        for (int r = 0; r < 4; ++r) {
            int m = quad * 4 + r;
            const float* xr = xref + (long)(b0 + m) * 520;
            float s = 0.f;
            #pragma unroll
            for (int j = 0; j < 8; ++j) {
                float z = 0.f;
                #pragma unroll
                for (int l = 0; l < 8; ++l) z += Q[j * 8 + l] * (xr[k * 8 + l] - xr[l]);
                s += Phi[k * 64 + i * 8 + j] * z;
            }
            f_reg[T][r] = -2.0f * s;
            u_reg[T][r] = 0.0f;
        }
    }

    // ---- register B-fragments: ALL 4 tiles, full K (256 unified regs) ----
    // hfrag[T][ks] = bf16 of H[colbase+T*16+lcol][ks*32+quad*8 .. +8]
    short8 hfrag[4][16];
    #pragma unroll
    for (int t = 0; t < 4; ++t) {
        const float* hrow = H + (long)(colbase + t * 16 + lcol) * 512;
        #pragma unroll
        for (int ks = 0; ks < 16; ++ks) {
            const float* hp = hrow + ks * 32 + quad * 8;
            short8 fr;
            #pragma unroll
            for (int j = 0; j < 8; ++j) fr[j] = (short)f32_to_bf16(hp[j]);
            hfrag[t][ks] = fr;
        }
    }
    __syncthreads();

    for (int it = 0; it < 100; ++it) {
        floatx4 acc[4];
        #pragma unroll
        for (int T = 0; T < 4; ++T) acc[T] = (floatx4){0.f, 0.f, 0.f, 0.f};

        // ---- K loop: a from LDS (only LDS reads in the kernel), B all-register ----
        #pragma unroll
        for (int ks = 0; ks < 16; ++ks) {
            short8 a = *(const short8*)&u_bf[lcol][ks * 32 + quad * 8];
            acc[0] = MFMA(a, hfrag[0][ks], acc[0]);
            acc[1] = MFMA(a, hfrag[1][ks], acc[1]);
            acc[2] = MFMA(a, hfrag[2][ks], acc[2]);
            acc[3] = MFMA(a, hfrag[3][ks], acc[3]);
        }

        // ---- update u master ----
        #pragma unroll
        for (int T = 0; T < 4; ++T)
            #pragma unroll
            for (int r = 0; r < 4; ++r) {
                float g  = acc[T][r] + f_reg[T][r];
                float un = u_reg[T][r] - 0.01f * g;
                un = fminf(1.0f, fmaxf(-1.0f, un));
                u_reg[T][r] = un;
            }

        __syncthreads();   // all waves done reading old u_bf
        #pragma unroll
        for (int T = 0; T < 4; ++T) {
            int c = colbase + T * 16 + lcol;
            #pragma unroll
            for (int r = 0; r < 4; ++r)
                u_bf[quad * 4 + r][c] = f32_to_bf16(u_reg[T][r]);
        }
        __syncthreads();   // new u_bf visible
    }

    // ---- write final u (fp32) ----
    #pragma unroll
    for (int T = 0; T < 4; ++T) {
        int c = colbase + T * 16 + lcol;
        #pragma unroll
        for (int r = 0; r < 4; ++r)
            out[(long)(b0 + quad * 4 + r) * 512 + c] = u_reg[T][r];
    }
}

extern "C" void kernel_launch(void* const* d_in, const int* in_sizes, int n_in,
                              void* d_out, int out_size, void* d_ws, size_t ws_size,
                              hipStream_t stream) {
    // inputs: 0=x0 (unused), 1=xref, 2=H, 3=Phi, 4=Q
    const float* xref = (const float*)d_in[1];
    const float* H    = (const float*)d_in[2];
    const float* Phi  = (const float*)d_in[3];
    const float* Q    = (const float*)d_in[4];

    pgd_kernel11<<<128, 512, 0, stream>>>(xref, H, Phi, Q, (float*)d_out);
}

// Round 8
// 253.582 us; speedup vs baseline: 2.3768x; 2.3768x over previous
//
#include <hip/hip_runtime.h>

// LinearMPC PGD, round 12: RESTORE the session-best R9 kernel (206 us steady-state).
// 128 blocks x 512 thr (8 waves, 2/SIMD). Wave w owns cols [w*64,+64) = 4 MFMA n-tiles:
//   T0,T1: bf16 B-fragments in registers (128 regs)
//   T2:    H rows in LDS (128 rows x 520-pad, 133 KB, iteration-invariant)
//   T3:    ks 0..7 in registers (32 regs), ks 8..15 loop-invariant loads (LICM'd, 32 regs)
// Two barriers per iteration, single u buffer.
// CLOSED directions (all measured): dbuf/single-barrier (R6/R7/R8: 403-852us);
// >192 H-regs or 2nd stream (R6/R10/R11: register cliff ~256 unified -> spill,
// WRITE_SIZE blowup, ~2x); prefetch depth (R9: null, compiler LICMs); swizzle
// (R7: conflict count layout-invariant, 4cy/b128 replay structural); wave/block
// rebalance (per-CU DS-op count invariant: a-reads scale with waves).
// Iteration floor: 256 b128 reads x ~16cy + writes ~640cy + barriers ~ 4750cy
// of 4944 measured -> ~96% LDS-pipe-bound. This is the structural roofline.

typedef unsigned short u16t;
typedef __attribute__((ext_vector_type(8))) short short8;
typedef __attribute__((ext_vector_type(4))) float floatx4;

#define HLDS_BYTES (128 * 520 * 2)                 // 133,120
#define UBF_BYTES  (16 * 520 * 2)                  // 16,640
#define DYN_LDS    (HLDS_BYTES + UBF_BYTES)        // 149,760 < 160 KiB

__device__ __forceinline__ u16t f32_to_bf16(float x) {
    unsigned int u = __builtin_bit_cast(unsigned int, x);
    u = (u + 0x7FFFu + ((u >> 16) & 1u)) >> 16;   // RNE
    return (u16t)u;
}

__global__ void convert_H_bf16(const float* __restrict__ H, u16t* __restrict__ Hb) {
    int idx = blockIdx.x * 256 + threadIdx.x;   // 1024 x 256 = 262144
    Hb[idx] = f32_to_bf16(H[idx]);
}

#define MFMA(a, b, c) __builtin_amdgcn_mfma_f32_16x16x32_bf16((a), (b), (c), 0, 0, 0)

__global__ __launch_bounds__(512, 2)
void pgd_kernel12(const float* __restrict__ xref,   // [2048][65][8]
                  const float* __restrict__ H,      // [512][512] fp32
                  const u16t*  __restrict__ Hb,     // [512][512] bf16
                  const float* __restrict__ Phi,    // [65][8][8]
                  const float* __restrict__ Q,      // [8][8]
                  float* __restrict__ out)          // [2048][512]
{
    extern __shared__ __align__(16) char smem[];
    u16t* Hlds = (u16t*)smem;                               // [128][520]
    u16t (*u_bf)[520] = (u16t(*)[520])(smem + HLDS_BYTES);  // [16][520]

    const int tid  = threadIdx.x;
    const int lane = tid & 63;
    const int w    = tid >> 6;        // wave 0..7
    const int quad = lane >> 4;       // 0..3
    const int lcol = lane & 15;       // 0..15
    const int b0   = blockIdx.x * 16;
    const int colbase = w * 64;

    // ---- stage T2 H-rows into LDS: ldsrow r holds H[(r>>4)*64 + 32 + (r&15)] ----
    for (int e = tid; e < 8192; e += 512) {
        int r = e >> 6, c = e & 63;
        *(short8*)&Hlds[r * 520 + c * 8] =
            *(const short8*)&Hb[(long)((r >> 4) * 64 + 32 + (r & 15)) * 512 + c * 8];
    }
    // ---- zero u_bf ----
    {
        u16t* ub = &u_bf[0][0];
        for (int e = tid; e < 8320; e += 512) ub[e] = 0;
    }

    // ---- register B-fragments: T0,T1 full (128 regs) ----
    short8 hfragA[2][16];
    #pragma unroll
    for (int t = 0; t < 2; ++t) {
        const float* hrow = H + (long)(colbase + t * 16 + lcol) * 512;
        #pragma unroll
        for (int ks = 0; ks < 16; ++ks) {
            const float* hp = hrow + ks * 32 + quad * 8;
            short8 fr;
            #pragma unroll
            for (int j = 0; j < 8; ++j) fr[j] = (short)f32_to_bf16(hp[j]);
            hfragA[t][ks] = fr;
        }
    }
    // ---- register B-fragments: T3 ks 0..7 (32 regs) ----
    short8 frag3[8];
    {
        const float* hrow = H + (long)(colbase + 48 + lcol) * 512;
        #pragma unroll
        for (int ks = 0; ks < 8; ++ks) {
            const float* hp = hrow + ks * 32 + quad * 8;
            short8 fr;
            #pragma unroll
            for (int j = 0; j < 8; ++j) fr[j] = (short)f32_to_bf16(hp[j]);
            frag3[ks] = fr;
        }
    }

    // ---- f (linear term) + u master, per-thread regs, C/D layout ----
    float f_reg[4][4], u_reg[4][4];
    #pragma unroll
    for (int T = 0; T < 4; ++T) {
        int c = colbase + T * 16 + lcol;
        int k = c >> 3, i = c & 7;
        #pragma unroll
        for (int r = 0; r < 4; ++r) {
            int m = quad * 4 + r;
            const float* xr = xref + (long)(b0 + m) * 520;
            float s = 0.f;
            #pragma unroll
            for (int j = 0; j < 8; ++j) {
                float z = 0.f;
                #pragma unroll
                for (int l = 0; l < 8; ++l) z += Q[j * 8 + l] * (xr[k * 8 + l] - xr[l]);
                s += Phi[k * 64 + i * 8 + j] * z;
            }
            f_reg[T][r] = -2.0f * s;
            u_reg[T][r] = 0.0f;
        }
    }
    __syncthreads();

    // streamed half of T3: ks 8..15 of row (colbase+48+lcol), iteration-invariant
    const u16t* hb3 = Hb + (long)(colbase + 48 + lcol) * 512;
    const u16t* h2  = Hlds + (w * 16 + lcol) * 520;

    for (int it = 0; it < 100; ++it) {
        // ---- all 8 streamed loads for ks 8..15 (loop-invariant, LICM'd) ----
        short8 sb[8];
        #pragma unroll
        for (int p = 0; p < 8; ++p)
            sb[p] = *(const short8*)&hb3[(8 + p) * 32 + quad * 8];

        floatx4 acc[4];
        #pragma unroll
        for (int T = 0; T < 4; ++T) acc[T] = (floatx4){0.f, 0.f, 0.f, 0.f};

        // ---- ks 0..7: all-register T3 ----
        #pragma unroll
        for (int ks = 0; ks < 8; ++ks) {
            short8 a  = *(const short8*)&u_bf[lcol][ks * 32 + quad * 8];
            short8 b2 = *(const short8*)&h2[ks * 32 + quad * 8];
            acc[0] = MFMA(a, hfragA[0][ks], acc[0]);
            acc[1] = MFMA(a, hfragA[1][ks], acc[1]);
            acc[2] = MFMA(a, b2, acc[2]);
            acc[3] = MFMA(a, frag3[ks], acc[3]);
        }
        // ---- ks 8..15: streamed T3 from sb[] (static indices) ----
        #pragma unroll
        for (int ks = 8; ks < 16; ++ks) {
            short8 a  = *(const short8*)&u_bf[lcol][ks * 32 + quad * 8];
            short8 b2 = *(const short8*)&h2[ks * 32 + quad * 8];
            acc[0] = MFMA(a, hfragA[0][ks], acc[0]);
            acc[1] = MFMA(a, hfragA[1][ks], acc[1]);
            acc[2] = MFMA(a, b2, acc[2]);
            acc[3] = MFMA(a, sb[ks - 8], acc[3]);
        }

        // ---- update u master ----
        #pragma unroll
        for (int T = 0; T < 4; ++T)
            #pragma unroll
            for (int r = 0; r < 4; ++r) {
                float g  = acc[T][r] + f_reg[T][r];
                float un = u_reg[T][r] - 0.01f * g;
                un = fminf(1.0f, fmaxf(-1.0f, un));
                u_reg[T][r] = un;
            }

        __syncthreads();   // all waves done reading old u_bf
        #pragma unroll
        for (int T = 0; T < 4; ++T) {
            int c = colbase + T * 16 + lcol;
            #pragma unroll
            for (int r = 0; r < 4; ++r)
                u_bf[quad * 4 + r][c] = f32_to_bf16(u_reg[T][r]);
        }
        __syncthreads();   // new u_bf visible
    }

    // ---- write final u (fp32) ----
    #pragma unroll
    for (int T = 0; T < 4; ++T) {
        int c = colbase + T * 16 + lcol;
        #pragma unroll
        for (int r = 0; r < 4; ++r)
            out[(long)(b0 + quad * 4 + r) * 512 + c] = u_reg[T][r];
    }
}

extern "C" void kernel_launch(void* const* d_in, const int* in_sizes, int n_in,
                              void* d_out, int out_size, void* d_ws, size_t ws_size,
                              hipStream_t stream) {
    // inputs: 0=x0 (unused), 1=xref, 2=H, 3=Phi, 4=Q
    const float* xref = (const float*)d_in[1];
    const float* H    = (const float*)d_in[2];
    const float* Phi  = (const float*)d_in[3];
    const float* Q    = (const float*)d_in[4];
    u16t* Hb = (u16t*)d_ws;                      // 512 KB

    (void)hipFuncSetAttribute((const void*)pgd_kernel12,
                              hipFuncAttributeMaxDynamicSharedMemorySize, DYN_LDS);

    convert_H_bf16<<<1024, 256, 0, stream>>>(H, Hb);
    pgd_kernel12<<<128, 512, DYN_LDS, stream>>>(xref, H, Hb, Phi, Q, (float*)d_out);
}